// Round 3
// baseline (603.993 us; speedup 1.0000x reference)
//
#include <hip/hip_runtime.h>

typedef __attribute__((ext_vector_type(8))) short short8;
typedef __attribute__((ext_vector_type(4))) float floatx4;

#define NB 65536      // total batches
#define BPB 8         // batches per block
#define STS 18        // st p-stride (elems): 16 p + 2 pad  (9 dwords/row)
#define WES 68        // wl f-row stride (elems)
#define WBS 1096      // wl b-stride: 16*68 + 8

static __device__ __forceinline__ ushort f2bf(float x) {
  union { float f; unsigned u; } v; v.f = x;
  unsigned r = v.u + 0x7FFFu + ((v.u >> 16) & 1u);   // round-nearest-even
  return (ushort)(r >> 16);
}
static __device__ __forceinline__ unsigned pk2(float a, float b) {
  return (unsigned)f2bf(a) | ((unsigned)f2bf(b) << 16);
}

// Build L = [inc(32 rows); I - d*inc^T inc (16 rows)] K-padded to 32 (bf16),
// and Mt[e][g][f] = M[e][f][g] (bf16).
__global__ void sheaf_prep(const float* __restrict__ inc,
                           const float* __restrict__ M,
                           const float* __restrict__ damp,
                           ushort* __restrict__ Mt,
                           ushort* __restrict__ L) {
  const int bid = blockIdx.x, tid = threadIdx.x;
  if (bid < 32) {
    const float* Me = M + (bid << 12);
    ushort* Mte = Mt + (bid << 12);
    for (int i = tid; i < 4096; i += 256) {
      int g = i >> 6, f = i & 63;
      Mte[(g << 6) + f] = f2bf(Me[(f << 6) + g]);
    }
  } else {
    for (int i = tid; i < 1024; i += 256) {       // rows 0-31: incidence
      int e = i >> 5, col = i & 31;
      L[(e << 5) + col] = (col < 16) ? f2bf(inc[(e << 4) + col]) : (ushort)0;
    }
    float d = damp[0];
    int p = tid >> 4, q = tid & 15;               // rows 32-47: I - d*dTd (fp32)
    float s = 0.f;
    for (int e = 0; e < 32; ++e)
      s += inc[(e << 4) + p] * inc[(e << 4) + q];
    float a = ((p == q) ? 1.f : 0.f) - d * s;
    L[((32 + p) << 5) + q] = f2bf(a);
    L[((32 + p) << 5) + 16 + q] = (ushort)0;
  }
}

__global__ __launch_bounds__(256, 4) void sheaf_main(
    const float* __restrict__ S,
    const ushort* __restrict__ Mt,
    const ushort* __restrict__ L,
    float* __restrict__ out) {
  __shared__ ushort st[512 * STS];    // [c=(b*64+f)][p] bf16, 18.4 KB
  __shared__ ushort wl[BPB * WBS];    // [b][eloc][f]   bf16, 17.5 KB
  __shared__ float h1s[4][BPB];

  const int tid  = threadIdx.x;
  const int lane = tid & 63;
  const int w    = tid >> 6;
  const int quad = lane >> 4;
  const int l15  = lane & 15;

  // ---- stage S^T into LDS: lane=f coalesced dword loads, packed b32 writes
  #pragma unroll
  for (int k = 0; k < 2; ++k) {
    int c = tid + (k << 8);                    // 0..511
    int b = c >> 6, f = c & 63;
    const float* src = S + (size_t)blockIdx.x * (BPB * 1024) + b * 1024 + f;
    float v[16];
    #pragma unroll
    for (int p = 0; p < 16; ++p) v[p] = src[p << 6];
    unsigned* dst = (unsigned*)st + c * 9;     // bank stride 9 -> conflict-free
    #pragma unroll
    for (int pp = 0; pp < 8; ++pp) dst[pp] = pk2(v[2 * pp], v[2 * pp + 1]);
  }

  // B-operand frags from L (L2-cached): lane n=l15, k=quad*8+j
  short8 bL0 = *(const short8*)(L + (l15) * 32 + (quad << 3));        // e 0-15
  short8 bL1 = *(const short8*)(L + (16 + l15) * 32 + (quad << 3));   // e 16-31
  short8 bLp = *(const short8*)(L + (32 + l15) * 32 + (quad << 3));   // diffusion (symmetric)

  __syncthreads();

  float hp = 0.f;

  for (int ec = 0; ec < 2; ++ec) {
    short8 bE = ec ? bL1 : bL0;
    // ---- step-L: A = st rows (m=c, k=p), B = L rows (n=e or p)
    for (int t = 0; t < 8; ++t) {
      int cb = ((w << 3) + t) << 4;            // c-tile base
      short8 aS;
      {
        union { short8 v; unsigned d[4]; } u;
        if (quad < 2) {
          const unsigned* row = (const unsigned*)st + (cb + l15) * 9 + (quad << 2);
          u.d[0] = row[0]; u.d[1] = row[1]; u.d[2] = row[2]; u.d[3] = row[3];
        } else {
          u.d[0] = 0u; u.d[1] = 0u; u.d[2] = 0u; u.d[3] = 0u;   // K-pad p>=16
        }
        aS = u.v;
      }
      int b  = cb >> 6;
      int fb = (cb & 63) + (quad << 2);
      floatx4 accW = {0.f, 0.f, 0.f, 0.f};
      accW = __builtin_amdgcn_mfma_f32_16x16x32_bf16(aS, bE, accW, 0, 0, 0);
      // D: col=l15=e-local, rows=c-local -> 4 consecutive f: pack b64
      uint2 pkv;
      pkv.x = pk2(accW[0], accW[1]);
      pkv.y = pk2(accW[2], accW[3]);
      *(uint2*)(wl + b * WBS + l15 * WES + fb) = pkv;
      if (ec == 0) {
        floatx4 accD = {0.f, 0.f, 0.f, 0.f};
        accD = __builtin_amdgcn_mfma_f32_16x16x32_bf16(aS, bLp, accD, 0, 0, 0);
        // D: col=l15=p, rows -> 4 consecutive f: float4 store
        float4 o; o.x = accD[0]; o.y = accD[1]; o.z = accD[2]; o.w = accD[3];
        *(float4*)(out + ((size_t)blockIdx.x * BPB + b) * 1024 + l15 * 64 + fb) = o;
      }
    }
    __syncthreads();

    // ---- step-2: coboundary norms; A = Mt[e] (m=g, k=f), B = wl (n=b, k=f)
    #pragma unroll
    for (int i = 0; i < 4; ++i) {
      int eloc = (w << 2) + i;
      int e = (ec << 4) + eloc;
      const ushort* MtE = Mt + (e << 12);
      // hoisted B-frags (lane b = l15&7; lanes 8-15 duplicate, outputs unused)
      short8 bW0, bW1;
      {
        const ushort* base = wl + (l15 & 7) * WBS + eloc * WES + (quad << 3);
        union { short8 v; uint2 d[2]; } u0, u1;
        u0.d[0] = *(const uint2*)(base);
        u0.d[1] = *(const uint2*)(base + 4);
        u1.d[0] = *(const uint2*)(base + 32);
        u1.d[1] = *(const uint2*)(base + 36);
        bW0 = u0.v; bW1 = u1.v;
      }
      float ss = 0.f;
      #pragma unroll
      for (int gt = 0; gt < 4; ++gt) {
        const ushort* ma = MtE + (((gt << 4) + l15) << 6) + (quad << 3);
        short8 a0 = *(const short8*)(ma);        // f 0..31 chunk
        short8 a1 = *(const short8*)(ma + 32);   // f 32..63 chunk
        floatx4 acc = {0.f, 0.f, 0.f, 0.f};
        acc = __builtin_amdgcn_mfma_f32_16x16x32_bf16(a0, bW0, acc, 0, 0, 0);
        acc = __builtin_amdgcn_mfma_f32_16x16x32_bf16(a1, bW1, acc, 0, 0, 0);
        ss += acc[0]*acc[0] + acc[1]*acc[1] + acc[2]*acc[2] + acc[3]*acc[3];
      }
      ss += __shfl_xor(ss, 16);   // sum over g across quads
      ss += __shfl_xor(ss, 32);
      hp += sqrtf(ss);            // per-(b=l15&7, e) norm (lanes 0-7 valid)
    }
    __syncthreads();              // before next ec overwrites wl
  }

  if (lane < 8) h1s[w][lane] = hp;
  __syncthreads();
  if (tid < 8) {
    float s = (h1s[0][tid] + h1s[1][tid] + h1s[2][tid] + h1s[3][tid]) * (1.f / 32.f);
    out[(size_t)NB * 1024 + (size_t)blockIdx.x * BPB + tid] = s;
  }
}

extern "C" void kernel_launch(void* const* d_in, const int* in_sizes, int n_in,
                              void* d_out, int out_size, void* d_ws, size_t ws_size,
                              hipStream_t stream) {
  const float* S   = (const float*)d_in[0];   // node_sections [B,P,F] fp32
  const float* inc = (const float*)d_in[1];   // incidence [E,P] fp32
  const float* M   = (const float*)d_in[2];   // sheaf_maps [E,F,F] fp32
  const float* dmp = (const float*)d_in[3];   // damping scalar fp32
  float* out = (float*)d_out;

  ushort* Mt = (ushort*)d_ws;        // 131072 bf16 elems (256 KB)
  ushort* L  = Mt + 131072;          // 48*32 bf16

  sheaf_prep<<<33, 256, 0, stream>>>(inc, M, dmp, Mt, L);
  sheaf_main<<<NB / BPB, 256, 0, stream>>>(S, Mt, L, out);
}